// Round 1
// baseline (4395.536 us; speedup 1.0000x reference)
//
#include <hip/hip_runtime.h>
#include <hip/hip_bf16.h>
#include <stdint.h>

// SimpleRNN: B=64, S=512, H=1024, V=128
// Phase 0: pack W_out -> bf16 MFMA-B-fragment layout in device global
// Phase 1: persistent 16-wg recurrence, W_hh slice resident in LDS (bf16),
//          h exchanged via global double buffer + device-scope barrier per step
// Phase 2: logits GEMM (hidden bf16 @ W_out bf16, fp32 accum) + b_out

#define Bz 64
#define Sz 512
#define Hz 1024
#define Vz 128
#define NWG 16
#define COLS 64   // Hz / NWG columns of W_hh per workgroup
#define WGT 512   // threads per wg (8 waves): 2 M-tiles x 4 K-splits

typedef __attribute__((ext_vector_type(8)))  short short8;
typedef __attribute__((ext_vector_type(16))) float f32x16;
typedef __attribute__((ext_vector_type(4)))  float f32x4;

// device-global scratch (ws_size unknown; .bss zero-init, rewritten every call)
__device__ unsigned short g_hbuf[2][Bz][Hz];            // 256 KB h double buffer (bf16 bits)
__device__ unsigned short g_hidden[(size_t)Bz*Sz*Hz];   // 64 MB hidden states (bf16 bits)
__device__ unsigned short g_wout[Hz*Vz];                // 256 KB packed W_out [kb][v][8]

__device__ __forceinline__ unsigned short f2bf(float f) {
  union { float f; unsigned u; } v; v.f = f;
  unsigned r = v.u + 0x7FFFu + ((v.u >> 16) & 1u);      // RNE
  return (unsigned short)(r >> 16);
}

// ---------------- Phase 0: pack W_out (H,V) fp32 -> [kb][v][8] bf16 ----------
__global__ void pack_wout(const float* __restrict__ W_out) {
  int gid = blockIdx.x * blockDim.x + threadIdx.x;      // 0..16383 (kb*128+v)
  int v  = gid & (Vz - 1);
  int kb = gid >> 7;
  unsigned short t[8];
#pragma unroll
  for (int j = 0; j < 8; ++j)
    t[j] = f2bf(W_out[(size_t)(kb * 8 + j) * Vz + v]);
  uint4 w;
  w.x = (unsigned)t[0] | ((unsigned)t[1] << 16);
  w.y = (unsigned)t[2] | ((unsigned)t[3] << 16);
  w.z = (unsigned)t[4] | ((unsigned)t[5] << 16);
  w.w = (unsigned)t[6] | ((unsigned)t[7] << 16);
  *(uint4*)&g_wout[(size_t)gid * 8] = w;
}

// ---------------- Phase 1: persistent recurrence -----------------------------
__global__ __launch_bounds__(WGT) void rnn_persistent(
    const int* __restrict__ x, const float* __restrict__ h0,
    const float* __restrict__ W_xh, const float* __restrict__ W_hh,
    const float* __restrict__ b_h, float* __restrict__ out,
    unsigned* __restrict__ ctr)
{
  // W slice, transposed fragment layout [kb=k/8][n][j] -> conflict-minimal ds_read_b128
  __shared__ unsigned short ldsW[128 * COLS * 8];       // 128 KB
  __shared__ float red[2][32][COLS];                    // 16 KB K-split reduction

  const int g    = blockIdx.x;        // 0..15
  const int n0g  = g * COLS;          // global column base of this wg's W slice
  const int tid  = threadIdx.x;
  const int lane = tid & 63;
  const int wv   = tid >> 6;          // 0..7
  const int mi   = wv & 1;            // M-tile (32 rows)
  const int ki   = wv >> 1;           // K-split (256 each)

  // ---- stage W_hh[:, n0g:n0g+64] -> ldsW (one-time) ----
  for (int idx = tid; idx < 128 * 64; idx += WGT) {
    int kb = idx >> 6, n = idx & 63;
    unsigned short t[8];
#pragma unroll
    for (int j = 0; j < 8; ++j)
      t[j] = f2bf(W_hh[(size_t)(kb * 8 + j) * Hz + n0g + n]);
    uint4 w;
    w.x = (unsigned)t[0] | ((unsigned)t[1] << 16);
    w.y = (unsigned)t[2] | ((unsigned)t[3] << 16);
    w.z = (unsigned)t[4] | ((unsigned)t[5] << 16);
    w.w = (unsigned)t[6] | ((unsigned)t[7] << 16);
    *(uint4*)&ldsW[(size_t)idx * 8] = w;
  }

  // ---- h0 -> g_hbuf[0] (each wg converts a 4096-elem slice) ----
  for (int idx = tid; idx < (Bz * Hz) / NWG; idx += WGT) {
    int e = g * (Bz * Hz / NWG) + idx;
    ((unsigned short*)g_hbuf)[e] = f2bf(h0[e]);
  }

  // device-scope barrier: monotonic counter, release arrival + acquire fence
  auto barrier = [&](unsigned target) {
    __syncthreads();  // all wg mem ops retired (compiler drains vmcnt before s_barrier)
    if (tid == 0) {
      __hip_atomic_fetch_add(ctr, 1u, __ATOMIC_RELEASE, __HIP_MEMORY_SCOPE_AGENT);
      while (__hip_atomic_load(ctr, __ATOMIC_RELAXED, __HIP_MEMORY_SCOPE_AGENT) < target)
        __builtin_amdgcn_s_sleep(2);
      __builtin_amdgcn_fence(__ATOMIC_ACQUIRE, "agent");  // invalidate stale L1/L2
    }
    __syncthreads();
  };
  barrier(NWG);  // h0 + all W slices staged everywhere

  // epilogue constants: thread -> (batch em, 8 cols at en0)
  const int em  = tid >> 3;          // 0..63
  const int en0 = (tid & 7) * 8;     // 0..56
  float bias[8];
#pragma unroll
  for (int j = 0; j < 8; ++j) bias[j] = b_h[n0g + en0 + j];

  // MFMA fragment address constants (v_mfma_f32_32x32x16_bf16)
  // A[m=lane&31][k=(lane>>5)*8+j], B[k=(lane>>5)*8+j][n=lane&31]
  const int am = mi * 32 + (lane & 31);
  const int aq = (lane >> 5) * 8;
  const int bn = lane & 31;
  const unsigned short* hb0 = (const unsigned short*)g_hbuf[0];
  const unsigned short* hb1 = (const unsigned short*)g_hbuf[1];

  for (int s = 0; s < Sz; ++s) {
    const int p = s & 1;
    const unsigned short* hsrc = p ? hb1 : hb0;

    // prefetch all 16 A-fragments (one latency wave)
    short8 a[16];
#pragma unroll
    for (int kst = 0; kst < 16; ++kst)
      a[kst] = *(const short8*)&hsrc[(size_t)am * Hz + ki * 256 + kst * 16 + aq];

    f32x16 acc0 = {};  // cols [0,32) of slice
    f32x16 acc1 = {};  // cols [32,64)
#pragma unroll
    for (int kst = 0; kst < 16; ++kst) {
      int kb = ki * 32 + kst * 2 + (lane >> 5);
      short8 b0 = *(const short8*)&ldsW[(size_t)(kb * 64 + bn) * 8];
      short8 b1 = *(const short8*)&ldsW[(size_t)(kb * 64 + 32 + bn) * 8];
      acc0 = __builtin_amdgcn_mfma_f32_32x32x16_bf16(a[kst], b0, acc0, 0, 0, 0);
      acc1 = __builtin_amdgcn_mfma_f32_32x32x16_bf16(a[kst], b1, acc1, 0, 0, 0);
    }

    // K-split reduction into red[mi][m][n]
    // C/D: col=lane&31, row=(reg&3)+8*(reg>>2)+4*(lane>>5)  [m74/m101]
    const int crow = 4 * (lane >> 5);
    if (ki == 0) {
#pragma unroll
      for (int r = 0; r < 16; ++r) {
        int m = crow + (r & 3) + 8 * (r >> 2);
        red[mi][m][bn]      = acc0[r];
        red[mi][m][32 + bn] = acc1[r];
      }
    }
    __syncthreads();
    for (int rnd = 1; rnd < 4; ++rnd) {
      if (ki == rnd) {
#pragma unroll
        for (int r = 0; r < 16; ++r) {
          int m = crow + (r & 3) + 8 * (r >> 2);
          red[mi][m][bn]      += acc0[r];
          red[mi][m][32 + bn] += acc1[r];
        }
      }
      __syncthreads();
    }

    // epilogue: z = matmul + emb + bias; h = tanh(z)
    int tok = x[em * Sz + s];
    const float* xe = &W_xh[(size_t)tok * Hz + n0g + en0];
    float xv[8];
    *(float4*)&xv[0] = *(const float4*)&xe[0];
    *(float4*)&xv[4] = *(const float4*)&xe[4];
    const float* rrow = &red[em >> 5][em & 31][en0];
    float z[8];
    *(float4*)&z[0] = *(const float4*)&rrow[0];
    *(float4*)&z[4] = *(const float4*)&rrow[4];
#pragma unroll
    for (int j = 0; j < 8; ++j) z[j] = tanhf(z[j] + xv[j] + bias[j]);

    unsigned pk[4];
#pragma unroll
    for (int j = 0; j < 4; ++j)
      pk[j] = (unsigned)f2bf(z[2 * j]) | ((unsigned)f2bf(z[2 * j + 1]) << 16);
    unsigned short* hdst = (unsigned short*)g_hbuf[p ^ 1] + (size_t)em * Hz + n0g + en0;
    *(uint4*)hdst = *(uint4*)pk;
    unsigned short* hidd = g_hidden + ((size_t)em * Sz + s) * Hz + n0g + en0;
    *(uint4*)hidd = *(uint4*)pk;
    if (s == Sz - 1) {
      float* hf = out + (size_t)Bz * Sz * Vz + (size_t)em * Hz + n0g + en0;
      *(float4*)&hf[0] = *(float4*)&z[0];
      *(float4*)&hf[4] = *(float4*)&z[4];
    }

    barrier((unsigned)NWG * (unsigned)(s + 2));
  }
}

// ---------------- Phase 2: logits = hidden @ W_out + b_out -------------------
__global__ __launch_bounds__(256) void logits_gemm(
    const float* __restrict__ b_out, float* __restrict__ out)
{
  __shared__ unsigned short ldsB[64 * Vz * 8];          // 128 KB: one K-chunk of W_out
  const int tid = threadIdx.x, lane = tid & 63, wv = tid >> 6;
  const int m0 = blockIdx.x * 64 + wv * 16;             // 16 hidden rows per wave
  const unsigned short* arow =
      g_hidden + (size_t)(m0 + (lane & 15)) * Hz + ((lane >> 4) * 8);

  f32x4 acc[8] = {};
  for (int c = 0; c < 2; ++c) {                         // K chunks of 512
    __syncthreads();
    const uint4* src = (const uint4*)&g_wout[(size_t)c * 64 * Vz * 8];
    uint4* dst = (uint4*)ldsB;
    for (int i = tid; i < 8192; i += 256) dst[i] = src[i];
    __syncthreads();

    short8 a[16];
#pragma unroll
    for (int kst = 0; kst < 16; ++kst)
      a[kst] = *(const short8*)&arow[c * 512 + kst * 32];
#pragma unroll
    for (int kst = 0; kst < 16; ++kst) {
      int kb = kst * 4 + (lane >> 4);
#pragma unroll
      for (int nt = 0; nt < 8; ++nt) {
        short8 b = *(const short8*)&ldsB[(size_t)(kb * Vz + nt * 16 + (lane & 15)) * 8];
        acc[nt] = __builtin_amdgcn_mfma_f32_16x16x32_bf16(a[kst], b, acc[nt], 0, 0, 0);
      }
    }
  }
  // C/D: col=lane&15, row=(lane>>4)*4+reg  [m89]
  const int col = lane & 15, q = lane >> 4;
#pragma unroll
  for (int nt = 0; nt < 8; ++nt) {
    float bo = b_out[nt * 16 + col];
#pragma unroll
    for (int r = 0; r < 4; ++r) {
      int m = m0 + q * 4 + r;
      out[(size_t)m * Vz + nt * 16 + col] = acc[nt][r] + bo;
    }
  }
}

// ---------------- host launcher ----------------------------------------------
extern "C" void kernel_launch(void* const* d_in, const int* in_sizes, int n_in,
                              void* d_out, int out_size, void* d_ws, size_t ws_size,
                              hipStream_t stream) {
  const int*   x     = (const int*)d_in[0];
  const float* h0    = (const float*)d_in[1];
  const float* W_xh  = (const float*)d_in[2];
  const float* W_hh  = (const float*)d_in[3];
  const float* b_h   = (const float*)d_in[4];
  const float* W_out = (const float*)d_in[5];
  const float* b_out = (const float*)d_in[6];
  float* out = (float*)d_out;

  hipMemsetAsync(d_ws, 0, 256, stream);                    // barrier counter
  pack_wout<<<64, 256, 0, stream>>>(W_out);
  rnn_persistent<<<NWG, WGT, 0, stream>>>(x, h0, W_xh, W_hh, b_h, out,
                                          (unsigned*)d_ws);
  logits_gemm<<<(Bz * Sz) / 64, 256, 0, stream>>>(b_out, out);
}